// Round 1
// baseline (388.612 us; speedup 1.0000x reference)
//
#include <hip/hip_runtime.h>
#include <cstdint>
#include <cstddef>

// ---------------- common types / helpers ----------------
typedef __attribute__((ext_vector_type(8))) short bf16x8;   // 8 bf16 in 4 VGPRs
typedef __attribute__((ext_vector_type(4))) float f32x4;

__device__ __forceinline__ uint16_t f2bf(float f) {
    uint32_t u = __float_as_uint(f);
    u += 0x7FFFu + ((u >> 16) & 1u);      // round-to-nearest-even
    return (uint16_t)(u >> 16);
}

__device__ __forceinline__ f32x4 mfma16(bf16x8 a, bf16x8 b, f32x4 c) {
    return __builtin_amdgcn_mfma_f32_16x16x32_bf16(a, b, c, 0, 0, 0);
}

// ---------------- weight transpose + cast: W[K,N] f32 -> Wt[N,K] bf16 ----------------
__global__ __launch_bounds__(256) void transpose_cast(const float* __restrict__ W,
                                                      uint16_t* __restrict__ Wt,
                                                      int K, int N) {
    __shared__ uint16_t tile[32][33];
    const int n0 = blockIdx.x * 32, k0 = blockIdx.y * 32;
    const int tx = threadIdx.x, ty = threadIdx.y;   // block (32,8)
#pragma unroll
    for (int j = 0; j < 4; ++j) {
        int k = k0 + ty + j * 8;
        tile[ty + j * 8][tx] = f2bf(W[(size_t)k * N + n0 + tx]);
    }
    __syncthreads();
#pragma unroll
    for (int j = 0; j < 4; ++j) {
        int n = n0 + ty + j * 8;
        Wt[(size_t)n * K + k0 + tx] = tile[tx][ty + j * 8];
    }
}

// ---------------- LayerNorm: f32 [rows,1024] -> bf16 ----------------
__global__ __launch_bounds__(256) void ln_kernel(const float* __restrict__ x,
                                                 const float* __restrict__ g,
                                                 const float* __restrict__ b,
                                                 uint16_t* __restrict__ out) {
    const int row = blockIdx.x;
    const int t = threadIdx.x;
    const float* xr = x + (size_t)row * 1024;
    float4 v = *(const float4*)(xr + t * 4);
    float s = v.x + v.y + v.z + v.w;
    float s2 = v.x * v.x + v.y * v.y + v.z * v.z + v.w * v.w;
#pragma unroll
    for (int off = 1; off < 64; off <<= 1) {
        s += __shfl_xor(s, off);
        s2 += __shfl_xor(s2, off);
    }
    __shared__ float sh[8];
    const int wv = t >> 6;
    if ((t & 63) == 0) { sh[wv] = s; sh[4 + wv] = s2; }
    __syncthreads();
    s = sh[0] + sh[1] + sh[2] + sh[3];
    s2 = sh[4] + sh[5] + sh[6] + sh[7];
    const float mu = s * (1.f / 1024.f);
    const float var = s2 * (1.f / 1024.f) - mu * mu;
    const float rs = rsqrtf(var + 1e-5f);
    float4 gg = *(const float4*)(g + t * 4);
    float4 bb = *(const float4*)(b + t * 4);
    ushort4 ov;
    ov.x = f2bf((v.x - mu) * rs * gg.x + bb.x);
    ov.y = f2bf((v.y - mu) * rs * gg.y + bb.y);
    ov.z = f2bf((v.z - mu) * rs * gg.z + bb.z);
    ov.w = f2bf((v.w - mu) * rs * gg.w + bb.w);
    *(ushort4*)(out + (size_t)row * 1024 + t * 4) = ov;
}

// ---------------- GEMM: C[M,N] = A[M,K](bf16) * Bt[N,K](bf16)^T (+epilogue) ----------------
// EPI 0: bf16 out, no bias
// EPI 1: f32 out = acc + bias[n] + resid[m,n]
// EPI 2: bf16 out = gelu_exact(acc + bias[n])
// 128x128 tile, BK=64, 4 waves (2x2), 4x4 16x16 frags per wave.
// LDS layout: [row][64] with 16B-granule XOR swizzle: granule' = granule ^ (row&7).
template <int EPI>
__global__ __launch_bounds__(256) void gemm_bt(const uint16_t* __restrict__ A,
                                               const uint16_t* __restrict__ Bt,
                                               const float* __restrict__ bias,
                                               const float* __restrict__ resid,
                                               void* __restrict__ outp,
                                               int M, int N, int K) {
    __shared__ uint16_t As[128 * 64];
    __shared__ uint16_t Bs[128 * 64];
    const int t = threadIdx.x, lane = t & 63, w = t >> 6;
    const int l16 = lane & 15, lhi = lane >> 4;
    const int wr = w >> 1, wc = w & 1;
    const int m0 = blockIdx.x * 128, n0 = blockIdx.y * 128;

    f32x4 acc[4][4];
    const f32x4 z = {0.f, 0.f, 0.f, 0.f};
#pragma unroll
    for (int mi = 0; mi < 4; ++mi)
#pragma unroll
        for (int ni = 0; ni < 4; ++ni) acc[mi][ni] = z;

    const int sr = t >> 3;            // 0..31
    const int sc = (t & 7) * 8;       // 0..56 step 8
    const uint16_t* Ag = A + (size_t)(m0 + sr) * K + sc;
    const uint16_t* Bg = Bt + (size_t)(n0 + sr) * K + sc;
    const int ssw = ((sc >> 3) ^ (sr & 7)) << 3;   // swizzled elem offset within row

    for (int kt = 0; kt < K; kt += 64) {
        __syncthreads();
#pragma unroll
        for (int p = 0; p < 4; ++p) {
            int r = p * 32 + sr;
            int4 av = *(const int4*)(Ag + (size_t)(p * 32) * K + kt);
            int4 bv = *(const int4*)(Bg + (size_t)(p * 32) * K + kt);
            *(int4*)&As[r * 64 + ssw] = av;
            *(int4*)&Bs[r * 64 + ssw] = bv;
        }
        __syncthreads();
#pragma unroll
        for (int kh = 0; kh < 2; ++kh) {
            bf16x8 af[4], bfr[4];
            const int gk = kh * 4 + lhi;   // k-granule index 0..7
#pragma unroll
            for (int mi = 0; mi < 4; ++mi) {
                int rr = wr * 64 + mi * 16 + l16;
                af[mi] = *(const bf16x8*)&As[rr * 64 + ((gk ^ (rr & 7)) << 3)];
            }
#pragma unroll
            for (int ni = 0; ni < 4; ++ni) {
                int rr = wc * 64 + ni * 16 + l16;
                bfr[ni] = *(const bf16x8*)&Bs[rr * 64 + ((gk ^ (rr & 7)) << 3)];
            }
#pragma unroll
            for (int mi = 0; mi < 4; ++mi)
#pragma unroll
                for (int ni = 0; ni < 4; ++ni)
                    acc[mi][ni] = mfma16(af[mi], bfr[ni], acc[mi][ni]);
        }
    }

    // epilogue: D row = 4*lhi + e, col = l16
#pragma unroll
    for (int mi = 0; mi < 4; ++mi) {
#pragma unroll
        for (int ni = 0; ni < 4; ++ni) {
#pragma unroll
            for (int e = 0; e < 4; ++e) {
                int gm = m0 + wr * 64 + mi * 16 + 4 * lhi + e;
                int gn = n0 + wc * 64 + ni * 16 + l16;
                float v = acc[mi][ni][e];
                if constexpr (EPI == 0) {
                    ((uint16_t*)outp)[(size_t)gm * N + gn] = f2bf(v);
                } else if constexpr (EPI == 1) {
                    v += bias[gn] + resid[(size_t)gm * N + gn];
                    ((float*)outp)[(size_t)gm * N + gn] = v;
                } else {
                    v += bias[gn];
                    float gl = 0.5f * v * (1.f + erff(v * 0.70710678118f));
                    ((uint16_t*)outp)[(size_t)gm * N + gn] = f2bf(gl);
                }
            }
        }
    }
}

// ---------------- flash attention: qkv bf16 [4096,3072] -> out bf16 [4096,1024] ----------------
// grid (qt=32, h=16, b=2), 256 threads = 4 waves, each wave owns 16 q-rows.
__global__ __launch_bounds__(256) void attn_kernel(const uint16_t* __restrict__ qkv,
                                                   uint16_t* __restrict__ aout) {
    const int qt = blockIdx.x, h = blockIdx.y, b = blockIdx.z;
    const int t = threadIdx.x, lane = t & 63, w = t >> 6;
    const int l16 = lane & 15, lhi = lane >> 4;
    __shared__ uint16_t Kt[64 * 64];       // [kk][d] granule-swizzled
    __shared__ uint16_t Vt[64 * 64];       // [d][kk] granule-swizzled
    __shared__ uint16_t Pl[4][16 * 64];    // per-wave P strip [qrow][kk] swizzled
    const int q0 = qt * 64;

    bf16x8 aq[2];
    {
        const uint16_t* qp = qkv + (size_t)(b * 2048 + q0 + w * 16 + l16) * 3072 + h * 64;
        aq[0] = *(const bf16x8*)(qp + 8 * lhi);
        aq[1] = *(const bf16x8*)(qp + 32 + 8 * lhi);
    }
    const f32x4 z = {0.f, 0.f, 0.f, 0.f};
    f32x4 oacc[4];
#pragma unroll
    for (int n = 0; n < 4; ++n) oacc[n] = z;
    float mrun[4], lrun[4];
#pragma unroll
    for (int e = 0; e < 4; ++e) { mrun[e] = -3e38f; lrun[e] = 0.f; }

    const int sr = t >> 3, sc = (t & 7) * 8;

    for (int kt2 = 0; kt2 < 32; ++kt2) {
        __syncthreads();
        const uint16_t* kb = qkv + (size_t)(b * 2048 + kt2 * 64) * 3072 + 1024 + h * 64;
#pragma unroll
        for (int p = 0; p < 2; ++p) {
            int r = p * 32 + sr;
            int4 kv = *(const int4*)(kb + (size_t)r * 3072 + sc);
            *(int4*)&Kt[r * 64 + (((sc >> 3) ^ (r & 7)) << 3)] = kv;
            int4 vv = *(const int4*)(kb + 1024 + (size_t)r * 3072 + sc);
            union { int4 v; uint16_t u[8]; } tv; tv.v = vv;
#pragma unroll
            for (int j = 0; j < 8; ++j) {
                int d = sc + j;
                Vt[d * 64 + ((((r >> 3) ^ (d & 7)) << 3) | (r & 7))] = tv.u[j];
            }
        }
        __syncthreads();

        // S = Q K^T  (S rows: q = 4*lhi+e within wave strip; cols kk = n*16+l16)
        f32x4 sacc[4];
#pragma unroll
        for (int n = 0; n < 4; ++n) sacc[n] = z;
#pragma unroll
        for (int n = 0; n < 4; ++n) {
#pragma unroll
            for (int kh = 0; kh < 2; ++kh) {
                int rr = n * 16 + l16;
                int gk = kh * 4 + lhi;
                bf16x8 bk = *(const bf16x8*)&Kt[rr * 64 + ((gk ^ (rr & 7)) << 3)];
                sacc[n] = mfma16(aq[kh], bk, sacc[n]);
            }
        }

        // online softmax
        float pv[4][4];
#pragma unroll
        for (int e = 0; e < 4; ++e) {
            float mx = -3e38f;
#pragma unroll
            for (int n = 0; n < 4; ++n) {
                float sv = sacc[n][e] * 0.125f;   // 1/sqrt(64)
                pv[n][e] = sv;
                mx = fmaxf(mx, sv);
            }
            mx = fmaxf(mx, __shfl_xor(mx, 1));
            mx = fmaxf(mx, __shfl_xor(mx, 2));
            mx = fmaxf(mx, __shfl_xor(mx, 4));
            mx = fmaxf(mx, __shfl_xor(mx, 8));
            float mnew = fmaxf(mrun[e], mx);
            float alpha = __expf(mrun[e] - mnew);
            mrun[e] = mnew;
            float ps = 0.f;
#pragma unroll
            for (int n = 0; n < 4; ++n) {
                float p = __expf(pv[n][e] - mnew);
                pv[n][e] = p;
                ps += p;
            }
            ps += __shfl_xor(ps, 1);
            ps += __shfl_xor(ps, 2);
            ps += __shfl_xor(ps, 4);
            ps += __shfl_xor(ps, 8);
            lrun[e] = lrun[e] * alpha + ps;
#pragma unroll
            for (int n = 0; n < 4; ++n) oacc[n][e] *= alpha;
        }

        // write P (bf16) to per-wave LDS strip, swizzled
#pragma unroll
        for (int e = 0; e < 4; ++e) {
            int r = 4 * lhi + e;
#pragma unroll
            for (int n = 0; n < 4; ++n) {
                int gsw = (n * 2 + (l16 >> 3)) ^ (r & 7);
                Pl[w][r * 64 + (gsw << 3) + (l16 & 7)] = f2bf(pv[n][e]);
            }
        }
        asm volatile("s_waitcnt lgkmcnt(0)" ::: "memory");

        // O += P V
        bf16x8 pa[2];
#pragma unroll
        for (int kh = 0; kh < 2; ++kh) {
            int gk = kh * 4 + lhi;
            pa[kh] = *(const bf16x8*)&Pl[w][l16 * 64 + ((gk ^ (l16 & 7)) << 3)];
        }
#pragma unroll
        for (int n = 0; n < 4; ++n) {
#pragma unroll
            for (int kh = 0; kh < 2; ++kh) {
                int d = n * 16 + l16;
                int gk = kh * 4 + lhi;
                bf16x8 bv = *(const bf16x8*)&Vt[d * 64 + ((gk ^ (d & 7)) << 3)];
                oacc[n] = mfma16(pa[kh], bv, oacc[n]);
            }
        }
    }

    // epilogue
#pragma unroll
    for (int n = 0; n < 4; ++n) {
#pragma unroll
        for (int e = 0; e < 4; ++e) {
            int qrow = q0 + w * 16 + 4 * lhi + e;
            float v = oacc[n][e] / lrun[e];
            aout[(size_t)(b * 2048 + qrow) * 1024 + h * 64 + n * 16 + l16] = f2bf(v);
        }
    }
}

// ---------------- launch ----------------
extern "C" void kernel_launch(void* const* d_in, const int* in_sizes, int n_in,
                              void* d_out, int out_size, void* d_ws, size_t ws_size,
                              hipStream_t stream) {
    const float* x      = (const float*)d_in[0];
    const float* ln1_g  = (const float*)d_in[1];
    const float* ln1_b  = (const float*)d_in[2];
    const float* qkv_w  = (const float*)d_in[3];
    const float* proj_w = (const float*)d_in[4];
    const float* proj_b = (const float*)d_in[5];
    const float* ln2_g  = (const float*)d_in[6];
    const float* ln2_b  = (const float*)d_in[7];
    const float* w1     = (const float*)d_in[8];
    const float* b1     = (const float*)d_in[9];
    const float* w2     = (const float*)d_in[10];
    const float* b2     = (const float*)d_in[11];
    float* out = (float*)d_out;

    char* ws = (char*)d_ws;
    size_t off = 0;
    auto alloc = [&](size_t bytes) {
        void* p = ws + off;
        off += (bytes + 255) & ~(size_t)255;
        return p;
    };
    uint16_t* wqkv_t  = (uint16_t*)alloc((size_t)3072 * 1024 * 2);
    uint16_t* wproj_t = (uint16_t*)alloc((size_t)1024 * 1024 * 2);
    uint16_t* w1_t    = (uint16_t*)alloc((size_t)4096 * 1024 * 2);
    uint16_t* w2_t    = (uint16_t*)alloc((size_t)1024 * 4096 * 2);
    float*    x2      = (float*)   alloc((size_t)4096 * 1024 * 4);
    uint16_t* lnb     = (uint16_t*)alloc((size_t)4096 * 1024 * 2);
    uint16_t* qkvb    = (uint16_t*)alloc((size_t)4096 * 3072 * 2);
    uint16_t* attnb   = (uint16_t*)alloc((size_t)4096 * 1024 * 2);
    uint16_t* h1      = qkvb;   // reuse qkvb+attnb region (32 MiB) after attention+proj

    dim3 tb(32, 8, 1);
    transpose_cast<<<dim3(3072 / 32, 1024 / 32), tb, 0, stream>>>(qkv_w, wqkv_t, 1024, 3072);
    transpose_cast<<<dim3(1024 / 32, 1024 / 32), tb, 0, stream>>>(proj_w, wproj_t, 1024, 1024);
    transpose_cast<<<dim3(4096 / 32, 1024 / 32), tb, 0, stream>>>(w1, w1_t, 1024, 4096);
    transpose_cast<<<dim3(1024 / 32, 4096 / 32), tb, 0, stream>>>(w2, w2_t, 4096, 1024);

    ln_kernel<<<4096, 256, 0, stream>>>(x, ln1_g, ln1_b, lnb);
    gemm_bt<0><<<dim3(32, 24), 256, 0, stream>>>(lnb, wqkv_t, nullptr, nullptr, qkvb, 4096, 3072, 1024);
    attn_kernel<<<dim3(32, 16, 2), 256, 0, stream>>>(qkvb, attnb);
    gemm_bt<1><<<dim3(32, 8), 256, 0, stream>>>(attnb, wproj_t, proj_b, x, x2, 4096, 1024, 1024);
    ln_kernel<<<4096, 256, 0, stream>>>(x2, ln2_g, ln2_b, lnb);
    gemm_bt<2><<<dim3(32, 32), 256, 0, stream>>>(lnb, w1_t, b1, nullptr, h1, 4096, 4096, 1024);
    gemm_bt<1><<<dim3(32, 8), 256, 0, stream>>>(h1, w2_t, b2, x2, out, 4096, 1024, 4096);
}

// Round 2
// 332.892 us; speedup vs baseline: 1.1674x; 1.1674x over previous
//
#include <hip/hip_runtime.h>
#include <cstdint>
#include <cstddef>

// ---------------- common types / helpers ----------------
typedef __attribute__((ext_vector_type(8))) short bf16x8;   // 8 bf16 in 4 VGPRs
typedef __attribute__((ext_vector_type(4))) short bf16x4;   // 4 bf16 in 2 VGPRs
typedef __attribute__((ext_vector_type(4))) float f32x4;

__device__ __forceinline__ uint16_t f2bf(float f) {
    uint32_t u = __float_as_uint(f);
    u += 0x7FFFu + ((u >> 16) & 1u);      // round-to-nearest-even
    return (uint16_t)(u >> 16);
}
__device__ __forceinline__ uint32_t bfr(float f) {          // cheap round (P only)
    return (__float_as_uint(f) + 0x8000u) >> 16;
}

__device__ __forceinline__ f32x4 mfma16(bf16x8 a, bf16x8 b, f32x4 c) {
    return __builtin_amdgcn_mfma_f32_16x16x32_bf16(a, b, c, 0, 0, 0);
}

// async global->LDS, 16B per lane; LDS dest = wave-uniform base + lane*16
__device__ __forceinline__ void async_copy16(const void* g, void* l) {
    __builtin_amdgcn_global_load_lds(
        (__attribute__((address_space(1))) void*)g,
        (__attribute__((address_space(3))) void*)l, 16, 0, 0);
}

typedef __attribute__((address_space(3))) const uint16_t lds_cu16;
// per-lane gather of 4 bf16 at byte addr, addr+32, addr+64, addr+96
__device__ __forceinline__ bf16x4 tr_read(lds_cu16* p) {
    bf16x4 d;
    asm volatile("ds_read_b64_tr_b16 %0, %1" : "=v"(d) : "v"(p));
    return d;
}
__device__ __forceinline__ bf16x8 cat8(bf16x4 lo, bf16x4 hi) {
    return __builtin_shufflevector(lo, hi, 0, 1, 2, 3, 4, 5, 6, 7);
}

// ---------------- weight transpose + cast: W[K,N] f32 -> Wt[N,K] bf16 ----------------
__global__ __launch_bounds__(256) void transpose_cast(const float* __restrict__ W,
                                                      uint16_t* __restrict__ Wt,
                                                      int K, int N) {
    __shared__ uint16_t tile[32][33];
    const int n0 = blockIdx.x * 32, k0 = blockIdx.y * 32;
    const int tx = threadIdx.x, ty = threadIdx.y;   // block (32,8)
#pragma unroll
    for (int j = 0; j < 4; ++j) {
        int k = k0 + ty + j * 8;
        tile[ty + j * 8][tx] = f2bf(W[(size_t)k * N + n0 + tx]);
    }
    __syncthreads();
#pragma unroll
    for (int j = 0; j < 4; ++j) {
        int n = n0 + ty + j * 8;
        Wt[(size_t)n * K + k0 + tx] = tile[tx][ty + j * 8];
    }
}

// ---------------- LayerNorm: f32 [rows,1024] -> bf16 ----------------
__global__ __launch_bounds__(256) void ln_kernel(const float* __restrict__ x,
                                                 const float* __restrict__ g,
                                                 const float* __restrict__ b,
                                                 uint16_t* __restrict__ out) {
    const int row = blockIdx.x;
    const int t = threadIdx.x;
    const float* xr = x + (size_t)row * 1024;
    float4 v = *(const float4*)(xr + t * 4);
    float s = v.x + v.y + v.z + v.w;
    float s2 = v.x * v.x + v.y * v.y + v.z * v.z + v.w * v.w;
#pragma unroll
    for (int off = 1; off < 64; off <<= 1) {
        s += __shfl_xor(s, off);
        s2 += __shfl_xor(s2, off);
    }
    __shared__ float sh[8];
    const int wv = t >> 6;
    if ((t & 63) == 0) { sh[wv] = s; sh[4 + wv] = s2; }
    __syncthreads();
    s = sh[0] + sh[1] + sh[2] + sh[3];
    s2 = sh[4] + sh[5] + sh[6] + sh[7];
    const float mu = s * (1.f / 1024.f);
    const float var = s2 * (1.f / 1024.f) - mu * mu;
    const float rs = rsqrtf(var + 1e-5f);
    float4 gg = *(const float4*)(g + t * 4);
    float4 bb = *(const float4*)(b + t * 4);
    ushort4 ov;
    ov.x = f2bf((v.x - mu) * rs * gg.x + bb.x);
    ov.y = f2bf((v.y - mu) * rs * gg.y + bb.y);
    ov.z = f2bf((v.z - mu) * rs * gg.z + bb.z);
    ov.w = f2bf((v.w - mu) * rs * gg.w + bb.w);
    *(ushort4*)(out + (size_t)row * 1024 + t * 4) = ov;
}

// ---------------- GEMM: C[M,N] = A[M,K](bf16) * Bt[N,K](bf16)^T (+epilogue) ----------------
// EPI 0: bf16 out  | EPI 1: f32 out = acc+bias+resid | EPI 2: bf16 out = gelu(acc+bias)
// m97 structure: global_load_lds width-16 staging (LDS linear write), source-side
// XOR granule swizzle so ds_read_b128 fragments are bank-balanced.
template <int EPI, int BM, int BN>
__global__ __launch_bounds__(256) void gemm_bt(const uint16_t* __restrict__ A,
                                               const uint16_t* __restrict__ Bt,
                                               const float* __restrict__ bias,
                                               const float* __restrict__ resid,
                                               void* __restrict__ outp,
                                               int M, int N, int K) {
    __shared__ uint16_t As[BM * 64];
    __shared__ uint16_t Bs[BN * 64];
    const int t = threadIdx.x, lane = t & 63, w = t >> 6;
    const int l16 = lane & 15, lhi = lane >> 4;
    const int wr = w >> 1, wc = w & 1;
    const int m0 = blockIdx.x * BM, n0 = blockIdx.y * BN;
    constexpr int MI = BM / 32, NI = BN / 32;

    f32x4 acc[MI][NI];
    const f32x4 z = {0.f, 0.f, 0.f, 0.f};
#pragma unroll
    for (int mi = 0; mi < MI; ++mi)
#pragma unroll
        for (int ni = 0; ni < NI; ++ni) acc[mi][ni] = z;

    // staging lane constants: row-in-8 = lane>>3, granule = lane&7, source granule swizzled
    const int srow = lane >> 3;
    const int sgs = ((lane & 7) ^ srow) << 3;   // source elem offset within row
    const uint16_t* Abase = A + (size_t)m0 * K;
    const uint16_t* Bbase = Bt + (size_t)n0 * K;

    for (int kt = 0; kt < K; kt += 64) {
        __syncthreads();   // prior iteration's LDS reads complete
#pragma unroll
        for (int p = 0; p < BM / 32; ++p) {
            int r0 = w * (BM / 4) + p * 8;
            async_copy16(Abase + (size_t)(r0 + srow) * K + kt + sgs, &As[r0 * 64]);
        }
#pragma unroll
        for (int p = 0; p < BN / 32; ++p) {
            int r0 = w * (BN / 4) + p * 8;
            async_copy16(Bbase + (size_t)(r0 + srow) * K + kt + sgs, &Bs[r0 * 64]);
        }
        __syncthreads();   // drains vmcnt -> LDS tile ready
#pragma unroll
        for (int kh = 0; kh < 2; ++kh) {
            const int gk = kh * 4 + lhi;           // k-granule 0..7
            const int gsw = (gk ^ (l16 & 7)) << 3; // swizzled LDS elem offset
            bf16x8 af[MI], bfr[NI];
#pragma unroll
            for (int mi = 0; mi < MI; ++mi) {
                int rr = wr * (BM / 2) + mi * 16 + l16;
                af[mi] = *(const bf16x8*)&As[rr * 64 + gsw];
            }
#pragma unroll
            for (int ni = 0; ni < NI; ++ni) {
                int rr = wc * (BN / 2) + ni * 16 + l16;
                bfr[ni] = *(const bf16x8*)&Bs[rr * 64 + gsw];
            }
#pragma unroll
            for (int mi = 0; mi < MI; ++mi)
#pragma unroll
                for (int ni = 0; ni < NI; ++ni)
                    acc[mi][ni] = mfma16(af[mi], bfr[ni], acc[mi][ni]);
        }
    }

    // epilogue: D row = 4*lhi + e, col = l16
#pragma unroll
    for (int mi = 0; mi < MI; ++mi) {
#pragma unroll
        for (int ni = 0; ni < NI; ++ni) {
#pragma unroll
            for (int e = 0; e < 4; ++e) {
                int gm = m0 + wr * (BM / 2) + mi * 16 + 4 * lhi + e;
                int gn = n0 + wc * (BN / 2) + ni * 16 + l16;
                float v = acc[mi][ni][e];
                if constexpr (EPI == 0) {
                    ((uint16_t*)outp)[(size_t)gm * N + gn] = f2bf(v);
                } else if constexpr (EPI == 1) {
                    v += bias[gn] + resid[(size_t)gm * N + gn];
                    ((float*)outp)[(size_t)gm * N + gn] = v;
                } else {
                    v += bias[gn];
                    float gl = 0.5f * v * (1.f + erff(v * 0.70710678118f));
                    ((uint16_t*)outp)[(size_t)gm * N + gn] = f2bf(gl);
                }
            }
        }
    }
}

// ---------------- flash attention: qkv bf16 [4096,3072] -> out bf16 [4096,1024] ----------------
// grid (qt=32, h=16, b=2), 256 threads = 4 waves, each wave owns 16 q-rows.
// K: [64][64] LDS, source-granule-swizzled, read as b128 fragments.
// V: subtiled [kk/4][d/16][4][16] LDS via per-lane-source global_load_lds, read via tr_b16.
// P: per-wave P^T strip [kk=64][q=16], packed uint2 writes, read via tr_b16.
__global__ __launch_bounds__(256) void attn_kernel(const uint16_t* __restrict__ qkv,
                                                   uint16_t* __restrict__ aout) {
    __shared__ uint16_t Kt[2][64 * 64];
    __shared__ uint16_t Vs[2][64 * 64];
    __shared__ uint16_t Pt[4][64 * 16];
    const int qt = blockIdx.x, h = blockIdx.y, b = blockIdx.z;
    const int t = threadIdx.x, lane = t & 63, w = t >> 6;
    const int l16 = lane & 15, lhi = lane >> 4;
    const int q0 = qt * 64;
    const uint16_t* base = qkv + (size_t)(b * 2048) * 3072 + h * 64;

    // Q fragments (16 q-rows per wave)
    bf16x8 aq[2];
    {
        const uint16_t* qp = base + (size_t)(q0 + w * 16 + l16) * 3072;
        aq[0] = *(const bf16x8*)(qp + 8 * lhi);
        aq[1] = *(const bf16x8*)(qp + 32 + 8 * lhi);
    }

    // staging lane constants
    const int krow = lane >> 3;                       // K: row-in-8
    const int kgs = ((lane & 7) ^ krow) << 3;         // K: swizzled source granule
    const int vkk = ((lane >> 5) << 2) | ((lane >> 1) & 3);            // V: kk within 8-row group
    const int vd  = (((lane >> 3) & 3) << 4) | ((lane & 1) << 3);      // V: d start

    auto stage = [&](int tile, int bufi) {
        const uint16_t* kb = base + (size_t)(tile * 64) * 3072 + 1024;
        const uint16_t* vb = base + (size_t)(tile * 64) * 3072 + 2048;
#pragma unroll
        for (int p = 0; p < 2; ++p) {
            int r0 = w * 16 + p * 8;
            async_copy16(kb + (size_t)(r0 + krow) * 3072 + kgs, &Kt[bufi][r0 * 64]);
        }
#pragma unroll
        for (int p = 0; p < 2; ++p) {
            int i = w * 2 + p;
            async_copy16(vb + (size_t)(i * 8 + vkk) * 3072 + vd, &Vs[bufi][i * 512]);
        }
    };

    const f32x4 z = {0.f, 0.f, 0.f, 0.f};
    f32x4 oacc[4];
#pragma unroll
    for (int n = 0; n < 4; ++n) oacc[n] = z;
    float mrun[4], lrun[4];
#pragma unroll
    for (int e = 0; e < 4; ++e) { mrun[e] = -1e30f; lrun[e] = 0.f; }
    const float cs = 0.18033688f;   // (1/sqrt(64)) * log2(e)

    stage(0, 0);
    __syncthreads();

    for (int tile = 0; tile < 32; ++tile) {
        const int cur = tile & 1;
        if (tile + 1 < 32) stage(tile + 1, cur ^ 1);   // prefetch next (hidden under compute)

        // ---- S = Q K^T ----
        f32x4 sacc[4];
#pragma unroll
        for (int n = 0; n < 4; ++n) sacc[n] = z;
#pragma unroll
        for (int n = 0; n < 4; ++n) {
#pragma unroll
            for (int kh = 0; kh < 2; ++kh) {
                const int gk = kh * 4 + lhi;
                const int rr = n * 16 + l16;
                bf16x8 bk = *(const bf16x8*)&Kt[cur][rr * 64 + ((gk ^ (l16 & 7)) << 3)];
                sacc[n] = mfma16(aq[kh], bk, sacc[n]);
            }
        }

        // ---- online softmax (exp2 domain, scale folded) ----
        float pv[4][4];
#pragma unroll
        for (int e = 0; e < 4; ++e) {
            float mx = fmaxf(fmaxf(sacc[0][e], sacc[1][e]), fmaxf(sacc[2][e], sacc[3][e]));
            mx = fmaxf(mx, __shfl_xor(mx, 1));
            mx = fmaxf(mx, __shfl_xor(mx, 2));
            mx = fmaxf(mx, __shfl_xor(mx, 4));
            mx = fmaxf(mx, __shfl_xor(mx, 8));
            const float mnew = fmaxf(mrun[e], mx);
            const float alpha = exp2f((mrun[e] - mnew) * cs);
            mrun[e] = mnew;
            const float mc = mnew * cs;
            float ps = 0.f;
#pragma unroll
            for (int n = 0; n < 4; ++n) {
                float p = exp2f(__fmaf_rn(sacc[n][e], cs, -mc));
                pv[n][e] = p;
                ps += p;
            }
            ps += __shfl_xor(ps, 1);
            ps += __shfl_xor(ps, 2);
            ps += __shfl_xor(ps, 4);
            ps += __shfl_xor(ps, 8);
            lrun[e] = lrun[e] * alpha + ps;
#pragma unroll
            for (int n = 0; n < 4; ++n) oacc[n][e] *= alpha;
        }

        // ---- write P^T strip: Pt[kk = n*16+l16][q = 4*lhi+e], packed 4 bf16 ----
#pragma unroll
        for (int n = 0; n < 4; ++n) {
            uint2 pk;
            pk.x = bfr(pv[n][0]) | (bfr(pv[n][1]) << 16);
            pk.y = bfr(pv[n][2]) | (bfr(pv[n][3]) << 16);
            *(uint2*)&Pt[w][((n * 16 + l16) << 4) + (lhi << 2)] = pk;
        }
        asm volatile("s_waitcnt lgkmcnt(0)" ::: "memory");
        __builtin_amdgcn_sched_barrier(0);

        // ---- tr_b16 fragment reads: P (A-operand) and V (B-operand) ----
        lds_cu16* ptb = (lds_cu16*)&Pt[w][0];
        lds_cu16* vtb = (lds_cu16*)&Vs[cur][0];
        bf16x8 pa[2], bv[4][2];
#pragma unroll
        for (int kh = 0; kh < 2; ++kh) {
            const int gk = kh * 4 + lhi;
            bf16x4 lo = tr_read(ptb + (gk << 7) + l16);        // kk = gk*8 + j
            bf16x4 hi = tr_read(ptb + (gk << 7) + 64 + l16);   // kk = gk*8+4 + j
            pa[kh] = cat8(lo, hi);
        }
#pragma unroll
        for (int n = 0; n < 4; ++n) {
#pragma unroll
            for (int kh = 0; kh < 2; ++kh) {
                const int gk = kh * 4 + lhi;
                bf16x4 lo = tr_read(vtb + ((gk * 2) << 8) + (n << 6) + l16);
                bf16x4 hi = tr_read(vtb + ((gk * 2 + 1) << 8) + (n << 6) + l16);
                bv[n][kh] = cat8(lo, hi);
            }
        }
        asm volatile("s_waitcnt lgkmcnt(0)" ::: "memory");
        __builtin_amdgcn_sched_barrier(0);

        // ---- O += P V ----
#pragma unroll
        for (int n = 0; n < 4; ++n)
#pragma unroll
            for (int kh = 0; kh < 2; ++kh)
                oacc[n] = mfma16(pa[kh], bv[n][kh], oacc[n]);

        __syncthreads();   // drains vmcnt (next-tile stage) + lgkm; releases cur buf
    }

    // epilogue
#pragma unroll
    for (int n = 0; n < 4; ++n) {
#pragma unroll
        for (int e = 0; e < 4; ++e) {
            int qrow = q0 + w * 16 + 4 * lhi + e;
            float v = oacc[n][e] / lrun[e];
            aout[(size_t)(b * 2048 + qrow) * 1024 + h * 64 + n * 16 + l16] = f2bf(v);
        }
    }
}

// ---------------- launch ----------------
extern "C" void kernel_launch(void* const* d_in, const int* in_sizes, int n_in,
                              void* d_out, int out_size, void* d_ws, size_t ws_size,
                              hipStream_t stream) {
    const float* x      = (const float*)d_in[0];
    const float* ln1_g  = (const float*)d_in[1];
    const float* ln1_b  = (const float*)d_in[2];
    const float* qkv_w  = (const float*)d_in[3];
    const float* proj_w = (const float*)d_in[4];
    const float* proj_b = (const float*)d_in[5];
    const float* ln2_g  = (const float*)d_in[6];
    const float* ln2_b  = (const float*)d_in[7];
    const float* w1     = (const float*)d_in[8];
    const float* b1     = (const float*)d_in[9];
    const float* w2     = (const float*)d_in[10];
    const float* b2     = (const float*)d_in[11];
    float* out = (float*)d_out;

    char* ws = (char*)d_ws;
    size_t off = 0;
    auto alloc = [&](size_t bytes) {
        void* p = ws + off;
        off += (bytes + 255) & ~(size_t)255;
        return p;
    };
    uint16_t* wqkv_t  = (uint16_t*)alloc((size_t)3072 * 1024 * 2);
    uint16_t* wproj_t = (uint16_t*)alloc((size_t)1024 * 1024 * 2);
    uint16_t* w1_t    = (uint16_t*)alloc((size_t)4096 * 1024 * 2);
    uint16_t* w2_t    = (uint16_t*)alloc((size_t)1024 * 4096 * 2);
    float*    x2      = (float*)   alloc((size_t)4096 * 1024 * 4);
    uint16_t* lnb     = (uint16_t*)alloc((size_t)4096 * 1024 * 2);
    uint16_t* qkvb    = (uint16_t*)alloc((size_t)4096 * 3072 * 2);
    uint16_t* attnb   = (uint16_t*)alloc((size_t)4096 * 1024 * 2);
    uint16_t* h1      = qkvb;   // reuse qkv region for ffn hidden

    dim3 tb(32, 8, 1);
    transpose_cast<<<dim3(3072 / 32, 1024 / 32), tb, 0, stream>>>(qkv_w, wqkv_t, 1024, 3072);
    transpose_cast<<<dim3(1024 / 32, 1024 / 32), tb, 0, stream>>>(proj_w, wproj_t, 1024, 1024);
    transpose_cast<<<dim3(4096 / 32, 1024 / 32), tb, 0, stream>>>(w1, w1_t, 1024, 4096);
    transpose_cast<<<dim3(1024 / 32, 4096 / 32), tb, 0, stream>>>(w2, w2_t, 4096, 1024);

    ln_kernel<<<4096, 256, 0, stream>>>(x, ln1_g, ln1_b, lnb);
    gemm_bt<0, 128, 128><<<dim3(32, 24), 256, 0, stream>>>(lnb, wqkv_t, nullptr, nullptr, qkvb, 4096, 3072, 1024);
    attn_kernel<<<dim3(32, 16, 2), 256, 0, stream>>>(qkvb, attnb);
    gemm_bt<1, 64, 128><<<dim3(64, 8), 256, 0, stream>>>(attnb, wproj_t, proj_b, x, x2, 4096, 1024, 1024);
    ln_kernel<<<4096, 256, 0, stream>>>(x2, ln2_g, ln2_b, lnb);
    gemm_bt<2, 128, 128><<<dim3(32, 32), 256, 0, stream>>>(lnb, w1_t, b1, nullptr, h1, 4096, 4096, 1024);
    gemm_bt<1, 64, 128><<<dim3(64, 8), 256, 0, stream>>>(h1, w2_t, b2, x2, out, 4096, 1024, 4096);
}

// Round 3
// 274.539 us; speedup vs baseline: 1.4155x; 1.2125x over previous
//
#include <hip/hip_runtime.h>
#include <cstdint>
#include <cstddef>

// ---------------- common types / helpers ----------------
typedef __attribute__((ext_vector_type(8))) short bf16x8;   // 8 bf16 in 4 VGPRs
typedef __attribute__((ext_vector_type(4))) short bf16x4;   // 4 bf16 in 2 VGPRs
typedef __attribute__((ext_vector_type(4))) float f32x4;

__device__ __forceinline__ uint16_t f2bf(float f) {
    uint32_t u = __float_as_uint(f);
    u += 0x7FFFu + ((u >> 16) & 1u);      // round-to-nearest-even
    return (uint16_t)(u >> 16);
}
__device__ __forceinline__ uint32_t bfr(float f) {          // cheap round (P only)
    return (__float_as_uint(f) + 0x8000u) >> 16;
}

__device__ __forceinline__ f32x4 mfma16(bf16x8 a, bf16x8 b, f32x4 c) {
    return __builtin_amdgcn_mfma_f32_16x16x32_bf16(a, b, c, 0, 0, 0);
}

// async global->LDS, 16B per lane; LDS dest = wave-uniform base + lane*16
__device__ __forceinline__ void async_copy16(const void* g, void* l) {
    __builtin_amdgcn_global_load_lds(
        (__attribute__((address_space(1))) void*)g,
        (__attribute__((address_space(3))) void*)l, 16, 0, 0);
}

typedef __attribute__((address_space(3))) const uint16_t lds_cu16;
// per-lane gather of 4 bf16 at byte addr, addr+32, addr+64, addr+96
__device__ __forceinline__ bf16x4 tr_read(lds_cu16* p) {
    bf16x4 d;
    asm volatile("ds_read_b64_tr_b16 %0, %1" : "=v"(d) : "v"(p));
    return d;
}
__device__ __forceinline__ bf16x8 cat8(bf16x4 lo, bf16x4 hi) {
    return __builtin_shufflevector(lo, hi, 0, 1, 2, 3, 4, 5, 6, 7);
}

// ---------------- weight transpose + cast: W[K,N] f32 -> Wt[N,K] bf16 ----------------
__global__ __launch_bounds__(256) void transpose_cast(const float* __restrict__ W,
                                                      uint16_t* __restrict__ Wt,
                                                      int K, int N) {
    __shared__ uint16_t tile[32][33];
    const int n0 = blockIdx.x * 32, k0 = blockIdx.y * 32;
    const int tx = threadIdx.x, ty = threadIdx.y;   // block (32,8)
#pragma unroll
    for (int j = 0; j < 4; ++j) {
        int k = k0 + ty + j * 8;
        tile[ty + j * 8][tx] = f2bf(W[(size_t)k * N + n0 + tx]);
    }
    __syncthreads();
#pragma unroll
    for (int j = 0; j < 4; ++j) {
        int n = n0 + ty + j * 8;
        Wt[(size_t)n * K + k0 + tx] = tile[tx][ty + j * 8];
    }
}

// ---------------- LayerNorm: f32 [rows,1024] -> bf16 ----------------
__global__ __launch_bounds__(256) void ln_kernel(const float* __restrict__ x,
                                                 const float* __restrict__ g,
                                                 const float* __restrict__ b,
                                                 uint16_t* __restrict__ out) {
    const int row = blockIdx.x;
    const int t = threadIdx.x;
    const float* xr = x + (size_t)row * 1024;
    float4 v = *(const float4*)(xr + t * 4);
    float s = v.x + v.y + v.z + v.w;
    float s2 = v.x * v.x + v.y * v.y + v.z * v.z + v.w * v.w;
#pragma unroll
    for (int off = 1; off < 64; off <<= 1) {
        s += __shfl_xor(s, off);
        s2 += __shfl_xor(s2, off);
    }
    __shared__ float sh[8];
    const int wv = t >> 6;
    if ((t & 63) == 0) { sh[wv] = s; sh[4 + wv] = s2; }
    __syncthreads();
    s = sh[0] + sh[1] + sh[2] + sh[3];
    s2 = sh[4] + sh[5] + sh[6] + sh[7];
    const float mu = s * (1.f / 1024.f);
    const float var = s2 * (1.f / 1024.f) - mu * mu;
    const float rs = rsqrtf(var + 1e-5f);
    float4 gg = *(const float4*)(g + t * 4);
    float4 bb = *(const float4*)(b + t * 4);
    ushort4 ov;
    ov.x = f2bf((v.x - mu) * rs * gg.x + bb.x);
    ov.y = f2bf((v.y - mu) * rs * gg.y + bb.y);
    ov.z = f2bf((v.z - mu) * rs * gg.z + bb.z);
    ov.w = f2bf((v.w - mu) * rs * gg.w + bb.w);
    *(ushort4*)(out + (size_t)row * 1024 + t * 4) = ov;
}

// ---------------- GEMM: C[M,N] = A[M,K](bf16) * Bt[N,K](bf16)^T (+epilogue) ----------------
// EPI 0: bf16 out  | EPI 1: f32 out = acc+bias+resid | EPI 2: bf16 out = gelu(acc+bias)
template <int EPI, int BM, int BN>
__global__ __launch_bounds__(256) void gemm_bt(const uint16_t* __restrict__ A,
                                               const uint16_t* __restrict__ Bt,
                                               const float* __restrict__ bias,
                                               const float* __restrict__ resid,
                                               void* __restrict__ outp,
                                               int M, int N, int K) {
    __shared__ uint16_t As[BM * 64];
    __shared__ uint16_t Bs[BN * 64];
    const int t = threadIdx.x, lane = t & 63, w = t >> 6;
    const int l16 = lane & 15, lhi = lane >> 4;
    const int wr = w >> 1, wc = w & 1;
    const int m0 = blockIdx.x * BM, n0 = blockIdx.y * BN;
    constexpr int MI = BM / 32, NI = BN / 32;

    f32x4 acc[MI][NI];
    const f32x4 z = {0.f, 0.f, 0.f, 0.f};
#pragma unroll
    for (int mi = 0; mi < MI; ++mi)
#pragma unroll
        for (int ni = 0; ni < NI; ++ni) acc[mi][ni] = z;

    const int srow = lane >> 3;
    const int sgs = ((lane & 7) ^ srow) << 3;   // source elem offset within row
    const uint16_t* Abase = A + (size_t)m0 * K;
    const uint16_t* Bbase = Bt + (size_t)n0 * K;

    for (int kt = 0; kt < K; kt += 64) {
        __syncthreads();
#pragma unroll
        for (int p = 0; p < BM / 32; ++p) {
            int r0 = w * (BM / 4) + p * 8;
            async_copy16(Abase + (size_t)(r0 + srow) * K + kt + sgs, &As[r0 * 64]);
        }
#pragma unroll
        for (int p = 0; p < BN / 32; ++p) {
            int r0 = w * (BN / 4) + p * 8;
            async_copy16(Bbase + (size_t)(r0 + srow) * K + kt + sgs, &Bs[r0 * 64]);
        }
        __syncthreads();
#pragma unroll
        for (int kh = 0; kh < 2; ++kh) {
            const int gk = kh * 4 + lhi;
            const int gsw = (gk ^ (l16 & 7)) << 3;
            bf16x8 af[MI], bfr[NI];
#pragma unroll
            for (int mi = 0; mi < MI; ++mi) {
                int rr = wr * (BM / 2) + mi * 16 + l16;
                af[mi] = *(const bf16x8*)&As[rr * 64 + gsw];
            }
#pragma unroll
            for (int ni = 0; ni < NI; ++ni) {
                int rr = wc * (BN / 2) + ni * 16 + l16;
                bfr[ni] = *(const bf16x8*)&Bs[rr * 64 + gsw];
            }
#pragma unroll
            for (int mi = 0; mi < MI; ++mi)
#pragma unroll
                for (int ni = 0; ni < NI; ++ni)
                    acc[mi][ni] = mfma16(af[mi], bfr[ni], acc[mi][ni]);
        }
    }

#pragma unroll
    for (int mi = 0; mi < MI; ++mi) {
#pragma unroll
        for (int ni = 0; ni < NI; ++ni) {
#pragma unroll
            for (int e = 0; e < 4; ++e) {
                int gm = m0 + wr * (BM / 2) + mi * 16 + 4 * lhi + e;
                int gn = n0 + wc * (BN / 2) + ni * 16 + l16;
                float v = acc[mi][ni][e];
                if constexpr (EPI == 0) {
                    ((uint16_t*)outp)[(size_t)gm * N + gn] = f2bf(v);
                } else if constexpr (EPI == 1) {
                    v += bias[gn] + resid[(size_t)gm * N + gn];
                    ((float*)outp)[(size_t)gm * N + gn] = v;
                } else {
                    v += bias[gn];
                    float gl = 0.5f * v * (1.f + erff(v * 0.70710678118f));
                    ((uint16_t*)outp)[(size_t)gm * N + gn] = f2bf(gl);
                }
            }
        }
    }
}

// ---------------- flash attention: qkv bf16 [4096,3072] -> out bf16 [4096,1024] ----------------
// Swapped-operand structure: S^T = mfma(K, Q) so each lane owns ONE q-row (q = l16);
// row-reduce = in-lane + 2 shuffles; m/l are per-lane scalars. PV also swapped:
// O^T = mfma(V^T, P^T), so rescale/divide stay in-lane.
__global__ __launch_bounds__(256) void attn_kernel(const uint16_t* __restrict__ qkv,
                                                   uint16_t* __restrict__ aout) {
    __shared__ uint16_t Kt[2][64 * 64];
    __shared__ uint16_t Vs[2][64 * 64];
    __shared__ uint16_t Pq[4][16 * 64];   // per-wave P [q=l16][kv=64], granule-swizzled
    const int qt = blockIdx.x, h = blockIdx.y, b = blockIdx.z;
    const int t = threadIdx.x, lane = t & 63, w = t >> 6;
    const int l16 = lane & 15, lhi = lane >> 4;
    const int q0 = qt * 64;
    const uint16_t* base = qkv + (size_t)(b * 2048) * 3072 + h * 64;

    // Q fragments: per-lane Q[q=l16][d = gk*8+j], gk = kh*4+lhi  (valid as B-operand)
    bf16x8 aq[2];
    {
        const uint16_t* qp = base + (size_t)(q0 + w * 16 + l16) * 3072;
        aq[0] = *(const bf16x8*)(qp + 8 * lhi);
        aq[1] = *(const bf16x8*)(qp + 32 + 8 * lhi);
    }

    // staging lane constants
    const int krow = lane >> 3;
    const int kgs = ((lane & 7) ^ krow) << 3;
    const int vkk = ((lane >> 5) << 2) | ((lane >> 1) & 3);
    const int vd  = (((lane >> 3) & 3) << 4) | ((lane & 1) << 3);

    auto stage = [&](int tile, int bufi) {
        const uint16_t* kb = base + (size_t)(tile * 64) * 3072 + 1024;
        const uint16_t* vb = base + (size_t)(tile * 64) * 3072 + 2048;
#pragma unroll
        for (int p = 0; p < 2; ++p) {
            int r0 = w * 16 + p * 8;
            async_copy16(kb + (size_t)(r0 + krow) * 3072 + kgs, &Kt[bufi][r0 * 64]);
        }
#pragma unroll
        for (int p = 0; p < 2; ++p) {
            int i = w * 2 + p;
            async_copy16(vb + (size_t)(i * 8 + vkk) * 3072 + vd, &Vs[bufi][i * 512]);
        }
    };

    const f32x4 z = {0.f, 0.f, 0.f, 0.f};
    f32x4 oaccT[4];          // O^T[d = n*16 + 4*lhi + e][q = l16]
#pragma unroll
    for (int n = 0; n < 4; ++n) oaccT[n] = z;
    float mrun = -1e30f, lrun = 0.f;      // per-lane (q = l16)
    const float cs = 0.18033688f;          // (1/sqrt(64)) * log2(e)

    stage(0, 0);
    __syncthreads();

    for (int tile = 0; tile < 32; ++tile) {
        const int cur = tile & 1;
        if (tile + 1 < 32) stage(tile + 1, cur ^ 1);   // prefetch next

        // ---- S^T = K Q^T : sacc[nk] rows kv = nk*16 + 4*lhi + e, col q = l16 ----
        f32x4 sacc[4];
#pragma unroll
        for (int nk = 0; nk < 4; ++nk) sacc[nk] = z;
#pragma unroll
        for (int nk = 0; nk < 4; ++nk) {
#pragma unroll
            for (int kh = 0; kh < 2; ++kh) {
                const int gk = kh * 4 + lhi;
                const int rr = nk * 16 + l16;
                bf16x8 bk = *(const bf16x8*)&Kt[cur][rr * 64 + ((gk ^ (l16 & 7)) << 3)];
                sacc[nk] = mfma16(bk, aq[kh], sacc[nk]);   // A=K, B=Q -> S^T
            }
        }

        // ---- per-lane online softmax (q = l16) ----
        float mx = -1e30f;
#pragma unroll
        for (int nk = 0; nk < 4; ++nk)
#pragma unroll
            for (int e = 0; e < 4; ++e) mx = fmaxf(mx, sacc[nk][e]);
        mx = fmaxf(mx, __shfl_xor(mx, 16));
        mx = fmaxf(mx, __shfl_xor(mx, 32));

        const bool keep = __all(mx - mrun <= 44.0f);   // defer-max: P bounded by 2^8
        float alpha = 1.f;
        if (!keep) {
            float mnew = fmaxf(mrun, mx);
            alpha = exp2f((mrun - mnew) * cs);
            mrun = mnew;
        }
        const float mc = mrun * cs;

        float p[4][4];
        float ps = 0.f;
#pragma unroll
        for (int nk = 0; nk < 4; ++nk)
#pragma unroll
            for (int e = 0; e < 4; ++e) {
                float pe = exp2f(__fmaf_rn(sacc[nk][e], cs, -mc));
                p[nk][e] = pe;
                ps += pe;
            }
        ps += __shfl_xor(ps, 16);
        ps += __shfl_xor(ps, 32);
        if (!keep) {
            lrun = lrun * alpha + ps;
#pragma unroll
            for (int n = 0; n < 4; ++n) oaccT[n] *= alpha;
        } else {
            lrun += ps;
        }

        // ---- write P[q=l16][kv] (swizzled granules), packed 8B ----
#pragma unroll
        for (int nk = 0; nk < 4; ++nk) {
            uint2 pk;
            pk.x = bfr(p[nk][0]) | (bfr(p[nk][1]) << 16);
            pk.y = bfr(p[nk][2]) | (bfr(p[nk][3]) << 16);
            const int g = nk * 2 + (lhi >> 1);           // kv granule
            *(uint2*)&Pq[w][l16 * 64 + ((g ^ (l16 & 7)) << 3) + ((lhi & 1) << 2)] = pk;
        }
        asm volatile("s_waitcnt lgkmcnt(0)" ::: "memory");
        __builtin_amdgcn_sched_barrier(0);

        // ---- read PA (B-operand, plain b128) and V^T (A-operand, tr_b16) ----
        bf16x8 pa[2];
#pragma unroll
        for (int kh = 0; kh < 2; ++kh) {
            const int gk = kh * 4 + lhi;
            pa[kh] = *(const bf16x8*)&Pq[w][l16 * 64 + ((gk ^ (l16 & 7)) << 3)];
        }
        lds_cu16* vtb = (lds_cu16*)&Vs[cur][0];
        bf16x8 bv[4][2];
#pragma unroll
        for (int n = 0; n < 4; ++n) {
#pragma unroll
            for (int kh = 0; kh < 2; ++kh) {
                const int gk = kh * 4 + lhi;
                bf16x4 lo = tr_read(vtb + ((gk * 2) << 8) + (n << 6) + l16);
                bf16x4 hi = tr_read(vtb + ((gk * 2 + 1) << 8) + (n << 6) + l16);
                bv[n][kh] = cat8(lo, hi);
            }
        }
        asm volatile("s_waitcnt lgkmcnt(0)" ::: "memory");
        __builtin_amdgcn_sched_barrier(0);

        // ---- O^T += V^T P^T ----
#pragma unroll
        for (int n = 0; n < 4; ++n)
#pragma unroll
            for (int kh = 0; kh < 2; ++kh)
                oaccT[n] = mfma16(bv[n][kh], pa[kh], oaccT[n]);

        __syncthreads();   // drains vmcnt (next-tile stage); releases cur buf
    }

    // epilogue: lane q = l16; d = n*16 + 4*lhi + e  -> 8B packed stores
    const float rl = 1.0f / lrun;
    const size_t orow = (size_t)(b * 2048 + q0 + w * 16 + l16) * 1024 + h * 64;
#pragma unroll
    for (int n = 0; n < 4; ++n) {
        ushort4 ov;
        ov.x = f2bf(oaccT[n][0] * rl);
        ov.y = f2bf(oaccT[n][1] * rl);
        ov.z = f2bf(oaccT[n][2] * rl);
        ov.w = f2bf(oaccT[n][3] * rl);
        *(ushort4*)&aout[orow + n * 16 + 4 * lhi] = ov;
    }
}

// ---------------- launch ----------------
extern "C" void kernel_launch(void* const* d_in, const int* in_sizes, int n_in,
                              void* d_out, int out_size, void* d_ws, size_t ws_size,
                              hipStream_t stream) {
    const float* x      = (const float*)d_in[0];
    const float* ln1_g  = (const float*)d_in[1];
    const float* ln1_b  = (const float*)d_in[2];
    const float* qkv_w  = (const float*)d_in[3];
    const float* proj_w = (const float*)d_in[4];
    const float* proj_b = (const float*)d_in[5];
    const float* ln2_g  = (const float*)d_in[6];
    const float* ln2_b  = (const float*)d_in[7];
    const float* w1     = (const float*)d_in[8];
    const float* b1     = (const float*)d_in[9];
    const float* w2     = (const float*)d_in[10];
    const float* b2     = (const float*)d_in[11];
    float* out = (float*)d_out;

    char* ws = (char*)d_ws;
    size_t off = 0;
    auto alloc = [&](size_t bytes) {
        void* p = ws + off;
        off += (bytes + 255) & ~(size_t)255;
        return p;
    };
    uint16_t* wqkv_t  = (uint16_t*)alloc((size_t)3072 * 1024 * 2);
    uint16_t* wproj_t = (uint16_t*)alloc((size_t)1024 * 1024 * 2);
    uint16_t* w1_t    = (uint16_t*)alloc((size_t)4096 * 1024 * 2);
    uint16_t* w2_t    = (uint16_t*)alloc((size_t)1024 * 4096 * 2);
    float*    x2      = (float*)   alloc((size_t)4096 * 1024 * 4);
    uint16_t* lnb     = (uint16_t*)alloc((size_t)4096 * 1024 * 2);
    uint16_t* qkvb    = (uint16_t*)alloc((size_t)4096 * 3072 * 2);
    uint16_t* attnb   = (uint16_t*)alloc((size_t)4096 * 1024 * 2);
    uint16_t* h1      = qkvb;   // reuse qkv region for ffn hidden

    dim3 tb(32, 8, 1);
    transpose_cast<<<dim3(3072 / 32, 1024 / 32), tb, 0, stream>>>(qkv_w, wqkv_t, 1024, 3072);
    transpose_cast<<<dim3(1024 / 32, 1024 / 32), tb, 0, stream>>>(proj_w, wproj_t, 1024, 1024);
    transpose_cast<<<dim3(4096 / 32, 1024 / 32), tb, 0, stream>>>(w1, w1_t, 1024, 4096);
    transpose_cast<<<dim3(1024 / 32, 4096 / 32), tb, 0, stream>>>(w2, w2_t, 4096, 1024);

    ln_kernel<<<4096, 256, 0, stream>>>(x, ln1_g, ln1_b, lnb);
    gemm_bt<0, 128, 128><<<dim3(32, 24), 256, 0, stream>>>(lnb, wqkv_t, nullptr, nullptr, qkvb, 4096, 3072, 1024);
    attn_kernel<<<dim3(32, 16, 2), 256, 0, stream>>>(qkvb, attnb);
    gemm_bt<1, 64, 128><<<dim3(64, 8), 256, 0, stream>>>(attnb, wproj_t, proj_b, x, x2, 4096, 1024, 1024);
    ln_kernel<<<4096, 256, 0, stream>>>(x2, ln2_g, ln2_b, lnb);
    gemm_bt<2, 128, 128><<<dim3(32, 32), 256, 0, stream>>>(lnb, w1_t, b1, nullptr, h1, 4096, 4096, 1024);
    gemm_bt<1, 64, 128><<<dim3(64, 8), 256, 0, stream>>>(h1, w2_t, b2, x2, out, 4096, 1024, 4096);
}